// Round 3
// baseline (149.240 us; speedup 1.0000x reference)
//
#include <hip/hip_runtime.h>

// Problem constants (from reference): B=1024, D_IN=64, D_HID=128.
#define BB      1024
#define DIN     64
#define DHID    128
#define NPAIRS  (1024.0f * 1024.0f)
#define BN_EPS  1e-5f

// ---------------------------------------------------------------------------
// K1: U[i][c] = x[i,:] . W1[0:64, c] + b1[c]
//     V[j][c] = x[j,:] . W1[64:128, c]
// Store Vj (j-major, for stats kernel) and Vt (c-major, for output kernel).
// Block 0 also zeroes sums[256] so k2 can atomicAdd into it (no memset node).
// Grid: 256 blocks x 256 threads; each block handles 4 rows of x.
// ---------------------------------------------------------------------------
__global__ __launch_bounds__(256) void k1_proj(
    const float* __restrict__ x, const float* __restrict__ W1,
    const float* __restrict__ b1,
    float* __restrict__ Ub, float* __restrict__ Vj, float* __restrict__ Vt,
    float* __restrict__ sums)
{
    __shared__ float xs[4][DIN];
    const int c     = threadIdx.x & 127;
    const int half  = threadIdx.x >> 7;      // 0..1
    const int rbase = blockIdx.x * 4;

    if (blockIdx.x == 0) sums[threadIdx.x] = 0.f;   // 256 floats, 1/thread

    // stage 4 x-rows (256 floats) into LDS: exactly one float per thread
    xs[threadIdx.x >> 6][threadIdx.x & 63] = x[rbase * DIN + threadIdx.x];
    __syncthreads();

    float u0 = 0.f, u1 = 0.f, v0 = 0.f, v1 = 0.f;
    const int r0 = half * 2;
    #pragma unroll 8
    for (int k = 0; k < DIN; ++k) {
        const float wt = W1[k * DHID + c];          // coalesced over c
        const float wb = W1[(DIN + k) * DHID + c];
        const float x0 = xs[r0][k];                  // LDS broadcast
        const float x1 = xs[r0 + 1][k];
        u0 = fmaf(x0, wt, u0); v0 = fmaf(x0, wb, v0);
        u1 = fmaf(x1, wt, u1); v1 = fmaf(x1, wb, v1);
    }
    const float bbv = b1[c];
    const int row0 = rbase + r0;
    Ub[row0 * DHID + c]       = u0 + bbv;
    Vj[row0 * DHID + c]       = v0;
    Vt[c * BB + row0]         = v0;
    Ub[(row0 + 1) * DHID + c] = u1 + bbv;
    Vj[(row0 + 1) * DHID + c] = v1;
    Vt[c * BB + row0 + 1]     = v1;
}

// ---------------------------------------------------------------------------
// K2: per-channel sum / sumsq of relu(U[i,c] + V[j,c]).
// Grid: dim3(128, 4) x 256 threads. Block = 8 i-rows x 256 j's.
// Thread: 4 channels (float4) x 8 u-rows IN REGISTERS, j-stride-8 lane.
// 96 VALU insts per 16B load -> latency covered; 512 blocks = 2 blocks/CU.
// Tail: LDS-reduce then one scalar atomicAdd per channel per block
// (256 addresses x 512 adds each -> ~1-2 us, replaces the k2b node).
// ---------------------------------------------------------------------------
__global__ __launch_bounds__(256) void k2_stats(
    const float* __restrict__ Ub, const float* __restrict__ Vj,
    float* __restrict__ sums)
{
    const int c0    = (threadIdx.x & 31) * 4;   // channel group
    const int jl    = threadIdx.x >> 5;         // 0..7
    const int ib    = blockIdx.x * 8;           // 8 i's
    const int jbase = blockIdx.y * 256;         // 256 j's

    float4 u[8];
    #pragma unroll
    for (int ii = 0; ii < 8; ++ii)
        u[ii] = *(const float4*)&Ub[(ib + ii) * DHID + c0];

    float4 s = {0.f, 0.f, 0.f, 0.f};
    float4 q = {0.f, 0.f, 0.f, 0.f};
    #pragma unroll 2
    for (int t = 0; t < 32; ++t) {
        const float4 v = *(const float4*)&Vj[(jbase + jl + 8 * t) * DHID + c0];
        #pragma unroll
        for (int ii = 0; ii < 8; ++ii) {
            float r;
            r = fmaxf(u[ii].x + v.x, 0.f); s.x += r; q.x = fmaf(r, r, q.x);
            r = fmaxf(u[ii].y + v.y, 0.f); s.y += r; q.y = fmaf(r, r, q.y);
            r = fmaxf(u[ii].z + v.z, 0.f); s.z += r; q.z = fmaf(r, r, q.z);
            r = fmaxf(u[ii].w + v.w, 0.f); s.w += r; q.w = fmaf(r, r, q.w);
        }
    }

    __shared__ float ls[8][DHID];
    __shared__ float lq[8][DHID];
    *(float4*)&ls[jl][c0] = s;
    *(float4*)&lq[jl][c0] = q;
    __syncthreads();

    if (threadIdx.x < 32) {
        float4 S = *(float4*)&ls[0][c0];
        float4 Q = *(float4*)&lq[0][c0];
        #pragma unroll
        for (int g = 1; g < 8; ++g) {
            S.x += ls[g][c0 + 0]; S.y += ls[g][c0 + 1];
            S.z += ls[g][c0 + 2]; S.w += ls[g][c0 + 3];
            Q.x += lq[g][c0 + 0]; Q.y += lq[g][c0 + 1];
            Q.z += lq[g][c0 + 2]; Q.w += lq[g][c0 + 3];
        }
        atomicAdd(&sums[c0 + 0], S.x); atomicAdd(&sums[c0 + 1], S.y);
        atomicAdd(&sums[c0 + 2], S.z); atomicAdd(&sums[c0 + 3], S.w);
        atomicAdd(&sums[DHID + c0 + 0], Q.x); atomicAdd(&sums[DHID + c0 + 1], Q.y);
        atomicAdd(&sums[DHID + c0 + 2], Q.z); atomicAdd(&sums[DHID + c0 + 3], Q.w);
    }
}

// ---------------------------------------------------------------------------
// K3: out[i,j] = t + sum_c relu(U[i,c] + V[j,c]) * s[c]
// Grid: dim3(128, 4) x 256 threads. Block = 8 i-rows x 256 j's.
// Thread: 2 i (LDS broadcast) x 4 j (float4 of c-major Vt): 24 VALU per
// 16B load, 3 LDS reads per c-iter. 512 blocks = 2 blocks/CU.
// ---------------------------------------------------------------------------
__global__ __launch_bounds__(256) void k3_out(
    const float* __restrict__ Ub, const float* __restrict__ Vt,
    const float* __restrict__ sums,
    const float* __restrict__ gamma, const float* __restrict__ beta,
    const float* __restrict__ W2, const float* __restrict__ b2,
    float* __restrict__ out)
{
    __shared__ float lsc[DHID];
    __shared__ float lus[8][DHID];
    __shared__ float ltp[DHID];
    __shared__ float lt;

    const int tid   = threadIdx.x;
    const int ib    = blockIdx.x * 8;
    const int jbase = blockIdx.y * 256;

    if (tid < DHID) {
        const float invN = 1.0f / NPAIRS;
        const float mean = sums[tid] * invN;
        const float var  = fmaxf(sums[DHID + tid] * invN - mean * mean, 0.f);
        const float inv  = rsqrtf(var + BN_EPS);
        const float gi   = gamma[tid] * inv;
        const float w2   = W2[tid];
        lsc[tid] = gi * w2;
        ltp[tid] = (beta[tid] - mean * gi) * w2;
    }
    // stage 8 rows of U (1024 floats) into LDS
    #pragma unroll
    for (int t = tid; t < 8 * DHID; t += 256)
        lus[t >> 7][t & 127] = Ub[(ib + (t >> 7)) * DHID + (t & 127)];
    __syncthreads();
    for (int off = 64; off >= 1; off >>= 1) {   // uniform control flow
        if (tid < off) ltp[tid] += ltp[tid + off];
        __syncthreads();
    }
    if (tid == 0) lt = ltp[0] + b2[0];
    __syncthreads();
    const float tconst = lt;

    const int i0 = (tid >> 6) * 2;              // 0,2,4,6 (wave-uniform)
    const int j0 = jbase + (tid & 63) * 4;      // 64 lanes x 16B contiguous

    float4 a0 = {0.f,0.f,0.f,0.f}, a1 = {0.f,0.f,0.f,0.f};
    #pragma unroll 4
    for (int c = 0; c < DHID; ++c) {
        const float4 v = *(const float4*)&Vt[c * BB + j0];  // coalesced 16B
        const float sc = lsc[c];                            // LDS broadcast
        const float u0 = lus[i0][c];                        // LDS broadcast
        const float u1 = lus[i0 + 1][c];
        a0.x = fmaf(fmaxf(u0 + v.x, 0.f), sc, a0.x);
        a0.y = fmaf(fmaxf(u0 + v.y, 0.f), sc, a0.y);
        a0.z = fmaf(fmaxf(u0 + v.z, 0.f), sc, a0.z);
        a0.w = fmaf(fmaxf(u0 + v.w, 0.f), sc, a0.w);
        a1.x = fmaf(fmaxf(u1 + v.x, 0.f), sc, a1.x);
        a1.y = fmaf(fmaxf(u1 + v.y, 0.f), sc, a1.y);
        a1.z = fmaf(fmaxf(u1 + v.z, 0.f), sc, a1.z);
        a1.w = fmaf(fmaxf(u1 + v.w, 0.f), sc, a1.w);
    }

    float4 o;
    o.x = a0.x + tconst; o.y = a0.y + tconst;
    o.z = a0.z + tconst; o.w = a0.w + tconst;
    *(float4*)&out[(ib + i0) * BB + j0] = o;
    o.x = a1.x + tconst; o.y = a1.y + tconst;
    o.z = a1.z + tconst; o.w = a1.w + tconst;
    *(float4*)&out[(ib + i0 + 1) * BB + j0] = o;
}

extern "C" void kernel_launch(void* const* d_in, const int* in_sizes, int n_in,
                              void* d_out, int out_size, void* d_ws, size_t ws_size,
                              hipStream_t stream) {
    const float* x     = (const float*)d_in[0];  // (1024, 64)
    const float* W1    = (const float*)d_in[1];  // (128, 128)
    const float* b1    = (const float*)d_in[2];  // (128,)
    const float* gamma = (const float*)d_in[3];  // (128,)
    const float* beta  = (const float*)d_in[4];  // (128,)
    const float* W2    = (const float*)d_in[5];  // (128,)
    const float* b2    = (const float*)d_in[6];  // (1,)
    float* out = (float*)d_out;                  // (1024*1024,)

    float* ws   = (float*)d_ws;
    float* Ub   = ws;                 // 1024*128
    float* Vj   = ws + 131072;        // 1024*128 (j-major)
    float* Vt   = ws + 262144;        // 128*1024 (c-major)
    float* sums = ws + 393216;        // 256 (sum | sumsq), zeroed by k1

    k1_proj<<<256, 256, 0, stream>>>(x, W1, b1, Ub, Vj, Vt, sums);
    k2_stats<<<dim3(128, 4), 256, 0, stream>>>(Ub, Vj, sums);
    k3_out<<<dim3(128, 4), 256, 0, stream>>>(Ub, Vt, sums, gamma, beta, W2, b2, out);
}

// Round 4
// 105.181 us; speedup vs baseline: 1.4189x; 1.4189x over previous
//
#include <hip/hip_runtime.h>

// Problem constants (from reference): B=1024, D_IN=64, D_HID=128.
#define BB      1024
#define DIN     64
#define DHID    128
#define NPAIRS  (1024.0f * 1024.0f)
#define BN_EPS  1e-5f

// ---------------------------------------------------------------------------
// K1: U[i][c] = x[i,:] . W1[0:64, c] + b1[c]
//     V[j][c] = x[j,:] . W1[64:128, c]
// Store Vj (j-major, for stats kernel) and Vt (c-major, for output kernel).
// Grid: 256 blocks x 256 threads; each block handles 4 rows of x.
// ---------------------------------------------------------------------------
__global__ __launch_bounds__(256) void k1_proj(
    const float* __restrict__ x, const float* __restrict__ W1,
    const float* __restrict__ b1,
    float* __restrict__ Ub, float* __restrict__ Vj, float* __restrict__ Vt)
{
    __shared__ float xs[4][DIN];
    const int c     = threadIdx.x & 127;
    const int half  = threadIdx.x >> 7;      // 0..1
    const int rbase = blockIdx.x * 4;

    // stage 4 x-rows (256 floats) into LDS: exactly one float per thread
    xs[threadIdx.x >> 6][threadIdx.x & 63] = x[rbase * DIN + threadIdx.x];
    __syncthreads();

    float u0 = 0.f, u1 = 0.f, v0 = 0.f, v1 = 0.f;
    const int r0 = half * 2;
    #pragma unroll 8
    for (int k = 0; k < DIN; ++k) {
        const float wt = W1[k * DHID + c];          // coalesced over c
        const float wb = W1[(DIN + k) * DHID + c];
        const float x0 = xs[r0][k];                  // LDS broadcast
        const float x1 = xs[r0 + 1][k];
        u0 = fmaf(x0, wt, u0); v0 = fmaf(x0, wb, v0);
        u1 = fmaf(x1, wt, u1); v1 = fmaf(x1, wb, v1);
    }
    const float bbv = b1[c];
    const int row0 = rbase + r0;
    Ub[row0 * DHID + c]       = u0 + bbv;
    Vj[row0 * DHID + c]       = v0;
    Vt[c * BB + row0]         = v0;
    Ub[(row0 + 1) * DHID + c] = u1 + bbv;
    Vj[(row0 + 1) * DHID + c] = v1;
    Vt[c * BB + row0 + 1]     = v1;
}

// ---------------------------------------------------------------------------
// K2: per-channel sum / sumsq of relu(U[i,c] + V[j,c]).
// Grid: dim3(128, 4) x 256 threads. Block = 8 i-rows x 256 j's.
// Thread: 4 channels (float4) x 8 u-rows IN REGISTERS, j-stride-8 lane.
// 128 VALU insts per 16B load; unroll 8 keeps ~8 loads in flight to cover
// ~500cy L2/L3 latency. 512 blocks = 2 blocks/CU = 8 waves/CU.
// Tail: per-block partial stores (NO atomics -- round-3 post-mortem: 131K
// contended atomicAdds cost ~40us of drain). partial[bid][0..255].
// ---------------------------------------------------------------------------
__global__ __launch_bounds__(256) void k2_stats(
    const float* __restrict__ Ub, const float* __restrict__ Vj,
    float* __restrict__ partial)
{
    const int c0    = (threadIdx.x & 31) * 4;   // channel group
    const int jl    = threadIdx.x >> 5;         // 0..7
    const int ib    = blockIdx.x * 8;           // 8 i's
    const int jbase = blockIdx.y * 256;         // 256 j's

    float4 u[8];
    #pragma unroll
    for (int ii = 0; ii < 8; ++ii)
        u[ii] = *(const float4*)&Ub[(ib + ii) * DHID + c0];

    float4 s = {0.f, 0.f, 0.f, 0.f};
    float4 q = {0.f, 0.f, 0.f, 0.f};
    const float* vp = Vj + (jbase + jl) * DHID + c0;
    #pragma unroll 8
    for (int t = 0; t < 32; ++t) {
        const float4 v = *(const float4*)&vp[t * 8 * DHID];
        #pragma unroll
        for (int ii = 0; ii < 8; ++ii) {
            float r;
            r = fmaxf(u[ii].x + v.x, 0.f); s.x += r; q.x = fmaf(r, r, q.x);
            r = fmaxf(u[ii].y + v.y, 0.f); s.y += r; q.y = fmaf(r, r, q.y);
            r = fmaxf(u[ii].z + v.z, 0.f); s.z += r; q.z = fmaf(r, r, q.z);
            r = fmaxf(u[ii].w + v.w, 0.f); s.w += r; q.w = fmaf(r, r, q.w);
        }
    }

    __shared__ float ls[8][DHID];
    __shared__ float lq[8][DHID];
    *(float4*)&ls[jl][c0] = s;
    *(float4*)&lq[jl][c0] = q;
    __syncthreads();

    if (threadIdx.x < 32) {
        float4 S = *(float4*)&ls[0][c0];
        float4 Q = *(float4*)&lq[0][c0];
        #pragma unroll
        for (int g = 1; g < 8; ++g) {
            S.x += ls[g][c0 + 0]; S.y += ls[g][c0 + 1];
            S.z += ls[g][c0 + 2]; S.w += ls[g][c0 + 3];
            Q.x += lq[g][c0 + 0]; Q.y += lq[g][c0 + 1];
            Q.z += lq[g][c0 + 2]; Q.w += lq[g][c0 + 3];
        }
        const int bid = blockIdx.y * 128 + blockIdx.x;   // 0..511
        *(float4*)&partial[bid * 256 + c0]        = S;
        *(float4*)&partial[bid * 256 + DHID + c0] = Q;
    }
}

// ---------------------------------------------------------------------------
// K2b: reduce partial[512][256] -> sums[256]. Plain stores, no atomics.
// Grid: 16 blocks x 256 threads, 16 columns per block.
// ---------------------------------------------------------------------------
__global__ __launch_bounds__(256) void k2b_reduce(
    const float* __restrict__ partial, float* __restrict__ sums)
{
    __shared__ float lred[16][17];
    const int cl   = threadIdx.x & 15;          // column-in-block
    const int rg   = threadIdx.x >> 4;          // 0..15 row group
    const int col  = blockIdx.x * 16 + cl;

    float acc = 0.f;
    #pragma unroll 8
    for (int t = 0; t < 32; ++t)
        acc += partial[(rg + 16 * t) * 256 + col];
    lred[rg][cl] = acc;
    __syncthreads();
    if (threadIdx.x < 16) {
        float a = 0.f;
        #pragma unroll
        for (int g = 0; g < 16; ++g) a += lred[g][threadIdx.x];
        sums[blockIdx.x * 16 + threadIdx.x] = a;
    }
}

// ---------------------------------------------------------------------------
// K3: out[i,j] = t + sum_c relu(U[i,c] + V[j,c]) * s[c]
// Grid: dim3(128, 4) x 256 threads. Block = 8 i-rows x 256 j's.
// Thread: 2 i x 4 j per c-iter: 1 global float4 (Vt) + 1 ds_read_b64 (U
// transposed [c][i]) + 24 VALU; unroll 8 for load pipelining.
// 512 blocks = 2 blocks/CU = 8 waves/CU.
// ---------------------------------------------------------------------------
__global__ __launch_bounds__(256) void k3_out(
    const float* __restrict__ Ub, const float* __restrict__ Vt,
    const float* __restrict__ sums,
    const float* __restrict__ gamma, const float* __restrict__ beta,
    const float* __restrict__ W2, const float* __restrict__ b2,
    float* __restrict__ out)
{
    __shared__ float lsc[DHID];
    __shared__ float lut[DHID][8];   // U transposed: [c][i-local]
    __shared__ float ltp[DHID];
    __shared__ float lt;

    const int tid   = threadIdx.x;
    const int ib    = blockIdx.x * 8;
    const int jbase = blockIdx.y * 256;

    if (tid < DHID) {
        const float invN = 1.0f / NPAIRS;
        const float mean = sums[tid] * invN;
        const float var  = fmaxf(sums[DHID + tid] * invN - mean * mean, 0.f);
        const float inv  = rsqrtf(var + BN_EPS);
        const float gi   = gamma[tid] * inv;
        const float w2   = W2[tid];
        lsc[tid] = gi * w2;
        ltp[tid] = (beta[tid] - mean * gi) * w2;
    }
    // stage 8 rows of U (1024 floats) into LDS, transposed to [c][i]
    #pragma unroll
    for (int t = tid; t < 8 * DHID; t += 256)
        lut[t & 127][t >> 7] = Ub[(ib + (t >> 7)) * DHID + (t & 127)];
    __syncthreads();
    // wave-0 shuffle reduction of ltp -> lt
    if (tid < 64) {
        float tl = ltp[tid] + ltp[tid + 64];
        #pragma unroll
        for (int off = 32; off >= 1; off >>= 1)
            tl += __shfl_down(tl, off, 64);
        if (tid == 0) lt = tl + b2[0];
    }
    __syncthreads();
    const float tconst = lt;

    const int i0 = (tid >> 6) * 2;              // 0,2,4,6 (wave-uniform)
    const int j0 = jbase + (tid & 63) * 4;      // 64 lanes x 16B contiguous

    float4 a0 = {0.f,0.f,0.f,0.f}, a1 = {0.f,0.f,0.f,0.f};
    const float* vtp = Vt + j0;
    #pragma unroll 8
    for (int c = 0; c < DHID; ++c) {
        const float4 v = *(const float4*)&vtp[c * BB];      // coalesced 16B
        const float2 uu = *(const float2*)&lut[c][i0];      // one ds_read_b64
        const float sc = lsc[c];                            // LDS broadcast
        a0.x = fmaf(fmaxf(uu.x + v.x, 0.f), sc, a0.x);
        a0.y = fmaf(fmaxf(uu.x + v.y, 0.f), sc, a0.y);
        a0.z = fmaf(fmaxf(uu.x + v.z, 0.f), sc, a0.z);
        a0.w = fmaf(fmaxf(uu.x + v.w, 0.f), sc, a0.w);
        a1.x = fmaf(fmaxf(uu.y + v.x, 0.f), sc, a1.x);
        a1.y = fmaf(fmaxf(uu.y + v.y, 0.f), sc, a1.y);
        a1.z = fmaf(fmaxf(uu.y + v.z, 0.f), sc, a1.z);
        a1.w = fmaf(fmaxf(uu.y + v.w, 0.f), sc, a1.w);
    }

    float4 o;
    o.x = a0.x + tconst; o.y = a0.y + tconst;
    o.z = a0.z + tconst; o.w = a0.w + tconst;
    *(float4*)&out[(ib + i0) * BB + j0] = o;
    o.x = a1.x + tconst; o.y = a1.y + tconst;
    o.z = a1.z + tconst; o.w = a1.w + tconst;
    *(float4*)&out[(ib + i0 + 1) * BB + j0] = o;
}

extern "C" void kernel_launch(void* const* d_in, const int* in_sizes, int n_in,
                              void* d_out, int out_size, void* d_ws, size_t ws_size,
                              hipStream_t stream) {
    const float* x     = (const float*)d_in[0];  // (1024, 64)
    const float* W1    = (const float*)d_in[1];  // (128, 128)
    const float* b1    = (const float*)d_in[2];  // (128,)
    const float* gamma = (const float*)d_in[3];  // (128,)
    const float* beta  = (const float*)d_in[4];  // (128,)
    const float* W2    = (const float*)d_in[5];  // (128,)
    const float* b2    = (const float*)d_in[6];  // (1,)
    float* out = (float*)d_out;                  // (1024*1024,)

    float* ws      = (float*)d_ws;
    float* Ub      = ws;                 // 1024*128
    float* Vj      = ws + 131072;        // 1024*128 (j-major)
    float* Vt      = ws + 262144;        // 128*1024 (c-major)
    float* partial = ws + 393216;        // 512*256 block partials
    float* sums    = ws + 524288;        // 256 (sum | sumsq)

    k1_proj<<<256, 256, 0, stream>>>(x, W1, b1, Ub, Vj, Vt);
    k2_stats<<<dim3(128, 4), 256, 0, stream>>>(Ub, Vj, partial);
    k2b_reduce<<<16, 256, 0, stream>>>(partial, sums);
    k3_out<<<dim3(128, 4), 256, 0, stream>>>(Ub, Vt, sums, gamma, beta, W2, b2, out);
}

// Round 6
// 99.577 us; speedup vs baseline: 1.4987x; 1.0563x over previous
//
#include <hip/hip_runtime.h>
#include <hip/hip_fp16.h>

// Problem constants (from reference): B=1024, D_IN=64, D_HID=128.
#define BB      1024
#define DIN     64
#define DHID    128
#define NPAIRS  (1024.0f * 1024.0f)
#define BN_EPS  1e-5f

// Native packed-fp16 vector type: clang emits v_pk_{add,mul,fma,max}_f16
// for operators / __builtin_elementwise_max on this type. (Round-5
// post-mortem: ROCm 7.2 lacks __hmax2/__hadd2/__hfma2 overloads.)
typedef _Float16 h2 __attribute__((ext_vector_type(2)));

struct __align__(16) H24 { h2 h[4]; };

__device__ __forceinline__ h2 mk_h2(float a, float b) {
    h2 r; r.x = (_Float16)a; r.y = (_Float16)b; return r;
}

// dot2 with fp32 accumulator: a.x*b.x + a.y*b.y + acc (v_dot2_f32_f16).
__device__ __forceinline__ float fdot2acc(h2 a, h2 b, float acc) {
#if __has_builtin(__builtin_amdgcn_fdot2)
    return __builtin_amdgcn_fdot2(a, b, acc, false);
#else
    return acc + (float)a.x * (float)b.x + (float)a.y * (float)b.y;
#endif
}

// ---------------------------------------------------------------------------
// K1: U[i][c] = x[i,:] . W1[0:64, c] + b1[c];  V[j][c] = x[j,:] . W1[64:, c]
// Emits packed fp16 only:
//   Uph[i*128+c]     = h2(u,u)                (replicated, for pk_add)
//   Vp2[jp*128+c]    = h2(v_2jp, v_2jp+1)     (jpair-major, for k2)
//   Vp3[c*512+jp]    = same data, c-major     (for k3)
// Grid: 256 blocks x 256 threads; block = 4 rows of x.
// ---------------------------------------------------------------------------
__global__ __launch_bounds__(256) void k1_proj(
    const float* __restrict__ x, const float* __restrict__ W1,
    const float* __restrict__ b1,
    h2* __restrict__ Uph, h2* __restrict__ Vp2, h2* __restrict__ Vp3)
{
    __shared__ float xs[4][DIN];
    const int c     = threadIdx.x & 127;
    const int hf    = threadIdx.x >> 7;      // 0..1
    const int rbase = blockIdx.x * 4;

    xs[threadIdx.x >> 6][threadIdx.x & 63] = x[rbase * DIN + threadIdx.x];
    __syncthreads();

    float u0 = 0.f, u1 = 0.f, v0 = 0.f, v1 = 0.f;
    const int r0 = hf * 2;
    #pragma unroll 8
    for (int k = 0; k < DIN; ++k) {
        const float wt = W1[k * DHID + c];          // coalesced over c
        const float wb = W1[(DIN + k) * DHID + c];
        const float x0 = xs[r0][k];                  // LDS broadcast
        const float x1 = xs[r0 + 1][k];
        u0 = fmaf(x0, wt, u0); v0 = fmaf(x0, wb, v0);
        u1 = fmaf(x1, wt, u1); v1 = fmaf(x1, wb, v1);
    }
    const float bbv = b1[c];
    const int row0 = rbase + r0;                     // even
    Uph[row0 * DHID + c]       = mk_h2(u0 + bbv, u0 + bbv);
    Uph[(row0 + 1) * DHID + c] = mk_h2(u1 + bbv, u1 + bbv);
    const h2 vp = mk_h2(v0, v1);
    const int jp = row0 >> 1;
    Vp2[jp * DHID + c]      = vp;
    Vp3[c * (BB / 2) + jp]  = vp;   // small scattered store, 256 KB total
}

// ---------------------------------------------------------------------------
// K2: per-channel sum / sumsq of relu(U[i,c] + V[j,c]), packed fp16.
// Grid: dim3(128, 4) x 256 threads. Block = 8 i x 128 jpairs (256 j).
// Thread: 4 channels x 8 u-rows in registers, jpair-stride-8 lane.
// Inner: pk_add + pk_max + 2x v_dot2_f32_f16 = 4 instr / 2 elements
// (fp32 accumulators -> stats precision preserved).
// Tail: per-block partial stores (NO atomics -- round-3 post-mortem: 131K
// contended atomicAdds cost ~40us of drain).
// ---------------------------------------------------------------------------
__global__ __launch_bounds__(256) void k2_stats(
    const h2* __restrict__ Uph, const h2* __restrict__ Vp2,
    float* __restrict__ partial)
{
    const int c0  = (threadIdx.x & 31) * 4;   // channel group
    const int jl  = threadIdx.x >> 5;         // 0..7
    const int ib  = blockIdx.x * 8;           // 8 i's
    const int jpb = blockIdx.y * 128;         // 128 jpairs

    H24 u[8];
    #pragma unroll
    for (int ii = 0; ii < 8; ++ii)
        u[ii] = *(const H24*)&Uph[(ib + ii) * DHID + c0];   // 16B aligned

    float s0=0.f,s1=0.f,s2=0.f,s3=0.f, q0=0.f,q1=0.f,q2=0.f,q3=0.f;
    const h2 zero2 = mk_h2(0.f, 0.f);
    const h2 one2  = mk_h2(1.f, 1.f);
    const h2* vp = Vp2 + (jpb + jl) * DHID + c0;
    #pragma unroll 4
    for (int t = 0; t < 16; ++t) {
        const H24 v = *(const H24*)&vp[t * 8 * DHID];
        #pragma unroll
        for (int ii = 0; ii < 8; ++ii) {
            h2 r;
            r = __builtin_elementwise_max(u[ii].h[0] + v.h[0], zero2);
            s0 = fdot2acc(r, one2, s0); q0 = fdot2acc(r, r, q0);
            r = __builtin_elementwise_max(u[ii].h[1] + v.h[1], zero2);
            s1 = fdot2acc(r, one2, s1); q1 = fdot2acc(r, r, q1);
            r = __builtin_elementwise_max(u[ii].h[2] + v.h[2], zero2);
            s2 = fdot2acc(r, one2, s2); q2 = fdot2acc(r, r, q2);
            r = __builtin_elementwise_max(u[ii].h[3] + v.h[3], zero2);
            s3 = fdot2acc(r, one2, s3); q3 = fdot2acc(r, r, q3);
        }
    }

    __shared__ float ls[8][DHID];
    __shared__ float lq[8][DHID];
    {
        float4 fs = {s0, s1, s2, s3};
        float4 fq = {q0, q1, q2, q3};
        *(float4*)&ls[jl][c0] = fs;
        *(float4*)&lq[jl][c0] = fq;
    }
    __syncthreads();

    if (threadIdx.x < 32) {
        float4 S = *(float4*)&ls[0][c0];
        float4 Q = *(float4*)&lq[0][c0];
        #pragma unroll
        for (int g = 1; g < 8; ++g) {
            S.x += ls[g][c0 + 0]; S.y += ls[g][c0 + 1];
            S.z += ls[g][c0 + 2]; S.w += ls[g][c0 + 3];
            Q.x += lq[g][c0 + 0]; Q.y += lq[g][c0 + 1];
            Q.z += lq[g][c0 + 2]; Q.w += lq[g][c0 + 3];
        }
        const int bid = blockIdx.y * 128 + blockIdx.x;   // 0..511
        *(float4*)&partial[bid * 256 + c0]        = S;
        *(float4*)&partial[bid * 256 + DHID + c0] = Q;
    }
}

// ---------------------------------------------------------------------------
// K2b: reduce partial[512][256] -> sums[256]. Plain stores, no atomics.
// Grid: 16 blocks x 256 threads, 16 columns per block.
// ---------------------------------------------------------------------------
__global__ __launch_bounds__(256) void k2b_reduce(
    const float* __restrict__ partial, float* __restrict__ sums)
{
    __shared__ float lred[16][17];
    const int cl   = threadIdx.x & 15;          // column-in-block
    const int rg   = threadIdx.x >> 4;          // 0..15 row group
    const int col  = blockIdx.x * 16 + cl;

    float acc = 0.f;
    #pragma unroll 8
    for (int t = 0; t < 32; ++t)
        acc += partial[(rg + 16 * t) * 256 + col];
    lred[rg][cl] = acc;
    __syncthreads();
    if (threadIdx.x < 16) {
        float a = 0.f;
        #pragma unroll
        for (int g = 0; g < 16; ++g) a += lred[g][threadIdx.x];
        sums[blockIdx.x * 16 + threadIdx.x] = a;
    }
}

// ---------------------------------------------------------------------------
// K3: out[i,j] = t + sum_c relu(U[i,c] + V[j,c]) * s[c], packed fp16.
// Grid: dim3(128, 4) x 256 threads. Block = 8 i x 256 j.
// Thread: 2 i x 2 jpairs (4 j). Inner per (i,jpair): pk_add+pk_max+pk_fma
// = 3 instr / 2 elements. fp16 accumulators flushed to fp32 every 32 c
// (caps fp16 drift at ~5e-3).
// ---------------------------------------------------------------------------
__global__ __launch_bounds__(256) void k3_out(
    const h2* __restrict__ Uph, const h2* __restrict__ Vp3,
    const float* __restrict__ sums,
    const float* __restrict__ gamma, const float* __restrict__ beta,
    const float* __restrict__ W2, const float* __restrict__ b2,
    float* __restrict__ out)
{
    __shared__ h2    lutp[DHID][8];  // U packed, transposed: [c][i-local]
    __shared__ h2    lsch[DHID];     // h2(s_c, s_c)
    __shared__ float ltp[DHID];
    __shared__ float lt;

    const int tid   = threadIdx.x;
    const int ib    = blockIdx.x * 8;
    const int jbase = blockIdx.y * 256;

    if (tid < DHID) {
        const float invN = 1.0f / NPAIRS;
        const float mean = sums[tid] * invN;
        const float var  = fmaxf(sums[DHID + tid] * invN - mean * mean, 0.f);
        const float inv  = rsqrtf(var + BN_EPS);
        const float gi   = gamma[tid] * inv;
        const float w2   = W2[tid];
        lsch[tid] = mk_h2(gi * w2, gi * w2);
        ltp[tid]  = (beta[tid] - mean * gi) * w2;
    }
    // stage 8 rows of packed U into LDS, transposed to [c][i]
    #pragma unroll
    for (int t = tid; t < 8 * DHID; t += 256)
        lutp[t & 127][t >> 7] = Uph[(ib + (t >> 7)) * DHID + (t & 127)];
    __syncthreads();
    // wave-0 shuffle reduction of ltp -> lt
    if (tid < 64) {
        float tl = ltp[tid] + ltp[tid + 64];
        #pragma unroll
        for (int off = 32; off >= 1; off >>= 1)
            tl += __shfl_down(tl, off, 64);
        if (tid == 0) lt = tl + b2[0];
    }
    __syncthreads();
    const float tconst = lt;

    const int i0   = (tid >> 6) * 2;              // 0,2,4,6 (wave-uniform)
    const int lane = tid & 63;
    const int jp0  = (jbase >> 1) + lane * 2;     // 2 adjacent jpairs = 4 j

    const h2 zero2 = mk_h2(0.f, 0.f);
    h2 a00 = zero2, a01 = zero2, a10 = zero2, a11 = zero2;
    float2 f00 = {0.f,0.f}, f01 = {0.f,0.f}, f10 = {0.f,0.f}, f11 = {0.f,0.f};

    for (int cb = 0; cb < 4; ++cb) {
        #pragma unroll 8
        for (int ci = 0; ci < 32; ++ci) {
            const int c = cb * 32 + ci;
            const h2 v0  = Vp3[c * (BB / 2) + jp0];      // merged 8B
            const h2 v1  = Vp3[c * (BB / 2) + jp0 + 1];
            const h2 sc  = lsch[c];                      // LDS broadcast
            const h2 uu0 = lutp[c][i0];                  // merged 8B
            const h2 uu1 = lutp[c][i0 + 1];
            a00 = __builtin_elementwise_max(uu0 + v0, zero2) * sc + a00;
            a01 = __builtin_elementwise_max(uu0 + v1, zero2) * sc + a01;
            a10 = __builtin_elementwise_max(uu1 + v0, zero2) * sc + a10;
            a11 = __builtin_elementwise_max(uu1 + v1, zero2) * sc + a11;
        }
        f00.x += (float)a00.x; f00.y += (float)a00.y; a00 = zero2;
        f01.x += (float)a01.x; f01.y += (float)a01.y; a01 = zero2;
        f10.x += (float)a10.x; f10.y += (float)a10.y; a10 = zero2;
        f11.x += (float)a11.x; f11.y += (float)a11.y; a11 = zero2;
    }

    const int j0 = jbase + lane * 4;
    float4 o;
    o.x = f00.x + tconst; o.y = f00.y + tconst;
    o.z = f01.x + tconst; o.w = f01.y + tconst;
    *(float4*)&out[(ib + i0) * BB + j0] = o;
    o.x = f10.x + tconst; o.y = f10.y + tconst;
    o.z = f11.x + tconst; o.w = f11.y + tconst;
    *(float4*)&out[(ib + i0 + 1) * BB + j0] = o;
}

extern "C" void kernel_launch(void* const* d_in, const int* in_sizes, int n_in,
                              void* d_out, int out_size, void* d_ws, size_t ws_size,
                              hipStream_t stream) {
    const float* x     = (const float*)d_in[0];  // (1024, 64)
    const float* W1    = (const float*)d_in[1];  // (128, 128)
    const float* b1    = (const float*)d_in[2];  // (128,)
    const float* gamma = (const float*)d_in[3];  // (128,)
    const float* beta  = (const float*)d_in[4];  // (128,)
    const float* W2    = (const float*)d_in[5];  // (128,)
    const float* b2    = (const float*)d_in[6];  // (1,)
    float* out = (float*)d_out;                  // (1024*1024,)

    float* ws = (float*)d_ws;
    h2* Uph        = (h2*)ws;                    // 1024*128 h2 (512 KB)
    h2* Vp2        = (h2*)(ws + 131072);         // 512*128 h2 (256 KB)
    h2* Vp3        = (h2*)(ws + 196608);         // 128*512 h2 (256 KB)
    float* partial = ws + 262144;                // 512*256 fp32
    float* sums    = ws + 393216;                // 256 (sum | sumsq)

    k1_proj<<<256, 256, 0, stream>>>(x, W1, b1, Uph, Vp2, Vp3);
    k2_stats<<<dim3(128, 4), 256, 0, stream>>>(Uph, Vp2, partial);
    k2b_reduce<<<16, 256, 0, stream>>>(partial, sums);
    k3_out<<<dim3(128, 4), 256, 0, stream>>>(Uph, Vp3, sums, gamma, beta, W2, b2, out);
}